// Round 4
// baseline (373.542 us; speedup 1.0000x reference)
//
#include <hip/hip_runtime.h>
#include <hip/hip_bf16.h>

// CrossAttention MI355X — round 3: operand-order-swapped GEMMs so every
// epilogue store is a contiguous f16x4/float4 per lane (MFMA C/D layout puts
// 4 consecutive m-rows in one lane; we arrange each GEMM so the contiguous
// output dim IS m). No scalar global stores anywhere.
//
//   out = softmax(Q (K Wk + bk)^T * scale) (V Wv + bv) Wo + bo
//   softmax(S) V = (exp(S) V) / rowsum(exp(S))   (scores tiny, no max-sub)
//
// GEMM: 128x128 tile, BK=32, 4 waves (2x2), global_load_lds w=16, unpadded
// LDS, 16 MFMA (f32_16x16x32_f16) + 8 ds_read_b128 per K-iter.
//
// Modes (all compute D[m][n] = A[m,:]·BT[n,:]):
//   0: K-proj  A=WkT(512x768)  B=kbf(16384x768) -> kpbf[kv][d]   f16x4 +bias[m]
//   1: outproj A=WoT(512x512)  B=ctx(16384x512) -> out[q][e]     f32x4 +bias[m]
//   2: V-proj  A=vbf(16384x768) B=WvT(512x768)  -> vpT[b][d][kv] f16x4 +bias[n]
//   3: S       A=kpbf(2048x512) B=qbf(2048x512) -> P~[q][kv]     f16x4 exp, rowsum[q] atomics
//   4: PV      A=vpT(512x2048)  B=P~(2048x2048) -> ctx[q][d]     f16x4 * 1/rowsum[q]

typedef _Float16 f16x8 __attribute__((ext_vector_type(8)));
typedef _Float16 f16x4 __attribute__((ext_vector_type(4)));
typedef float    f32x4 __attribute__((ext_vector_type(4)));

#define B_    8
#define LQ_   2048
#define LKV_  2048
#define DQ_   512
#define DC_   768

#define AS1 __attribute__((address_space(1)))
#define AS3 __attribute__((address_space(3)))

__device__ __forceinline__ void gload16(const void* g, void* l) {
    __builtin_amdgcn_global_load_lds((const AS1 void*)g, (AS3 void*)l, 16, 0, 0);
}

// ------------------------------------------------- fused q/k/v pack f32->f16
__global__ __launch_bounds__(256) void pack_qkv(const float* __restrict__ q,
                                                const float* __restrict__ k,
                                                const float* __restrict__ v,
                                                _Float16* __restrict__ qo,
                                                _Float16* __restrict__ ko,
                                                _Float16* __restrict__ vo) {
    const size_t NQ  = (size_t)B_ * LQ_ * DQ_;
    const size_t NKV = (size_t)B_ * LKV_ * DC_;
    size_t i = ((size_t)blockIdx.x * 256 + threadIdx.x) * 8;
    const float* src; _Float16* dst; size_t off;
    if (i < NQ)            { src = q; dst = qo; off = i; }
    else if (i < NQ + NKV) { src = k; dst = ko; off = i - NQ; }
    else                   { src = v; dst = vo; off = i - NQ - NKV; }
    float4 a = *(const float4*)(src + off);
    float4 b = *(const float4*)(src + off + 4);
    f16x8 h = { (_Float16)a.x, (_Float16)a.y, (_Float16)a.z, (_Float16)a.w,
                (_Float16)b.x, (_Float16)b.y, (_Float16)b.z, (_Float16)b.w };
    *(f16x8*)(dst + off) = h;
}

// ------------------------------------------------- fused weight transpose+cvt
__global__ __launch_bounds__(256) void pack_w(const float* __restrict__ Wk,
                                              const float* __restrict__ Wv,
                                              const float* __restrict__ Wo,
                                              _Float16* __restrict__ WkT,
                                              _Float16* __restrict__ WvT,
                                              _Float16* __restrict__ WoT) {
    const int NKW = DC_ * DQ_;   // 393216
    int id = blockIdx.x * 256 + threadIdx.x;
    const float* W; _Float16* WT; int off, K;
    if (id < NKW)           { W = Wk; WT = WkT; off = id;           K = DC_; }
    else if (id < 2 * NKW)  { W = Wv; WT = WvT; off = id - NKW;     K = DC_; }
    else                    { W = Wo; WT = WoT; off = id - 2 * NKW; K = DQ_; }
    int k = off / DQ_, n = off - k * DQ_;
    WT[(size_t)n * K + k] = (_Float16)W[off];
}

// ---------------------------------------------------------------- GEMM 128x128
template <int MODE>
__global__ __launch_bounds__(256, 3) void gemm128(
        const _Float16* __restrict__ A, const _Float16* __restrict__ BT,
        const float* __restrict__ bias, float* __restrict__ rsum,
        void* __restrict__ C, int M, int N, int K,
        long sAb, long sBb, long sCb) {
    __shared__ _Float16 As[128 * 32];   // 8 KB, unpadded (global_load_lds layout)
    __shared__ _Float16 Bs[128 * 32];   // 8 KB
    const int z = blockIdx.z;
    const _Float16* Ab = A + (size_t)z * sAb;
    const _Float16* Bb = BT + (size_t)z * sBb;
    const int m0 = blockIdx.x * 128, n0 = blockIdx.y * 128;
    const int tid = threadIdx.x, wave = tid >> 6, lane = tid & 63;
    const int l = lane & 15, quad = lane >> 4;
    const int wr = wave >> 1, wc = wave & 1;

    f32x4 acc[4][4] = {};

    const int srow = lane >> 2;           // 0..15 within 16-row chunk
    const int scol = (lane & 3) * 8;      // halfs 0,8,16,24

    for (int k0 = 0; k0 < K; k0 += 32) {
#pragma unroll
        for (int c0 = 0; c0 < 2; c0++) {
            int c = wave + c0 * 4;
            gload16(Ab + (size_t)(m0 + c * 16 + srow) * K + k0 + scol, &As[c * 512]);
            gload16(Bb + (size_t)(n0 + c * 16 + srow) * K + k0 + scol, &Bs[c * 512]);
        }
        __syncthreads();
        f16x8 af[4], bf[4];
#pragma unroll
        for (int t = 0; t < 4; t++) {
            af[t] = *(const f16x8*)&As[(wr * 64 + t * 16 + l) * 32 + quad * 8];
            bf[t] = *(const f16x8*)&Bs[(wc * 64 + t * 16 + l) * 32 + quad * 8];
        }
#pragma unroll
        for (int mt = 0; mt < 4; mt++)
#pragma unroll
            for (int nt = 0; nt < 4; nt++)
                acc[mt][nt] = __builtin_amdgcn_mfma_f32_16x16x32_f16(af[mt], bf[nt], acc[mt][nt], 0, 0, 0);
        __syncthreads();
    }

    // ---------------- epilogue (all stores vectorized along m)
    const float scale = 0.044194173824159216f;   // 1/sqrt(512)

    if (MODE == 2) {
        // D[kv][d] -> vpT[b][d][kv], f16x4 along kv
        _Float16* C16 = (_Float16*)C;
#pragma unroll
        for (int nt = 0; nt < 4; nt++) {
            const int d = n0 + wc * 64 + nt * 16 + l;
            const float bv = bias[d];
#pragma unroll
            for (int mt = 0; mt < 4; mt++) {
                const int mg = m0 + wr * 64 + mt * 16 + quad * 4;
                const int b = mg >> 11, kv = mg & 2047;
                f16x4 v4;
#pragma unroll
                for (int r = 0; r < 4; r++) v4[r] = (_Float16)(acc[mt][nt][r] + bv);
                *(f16x4*)(C16 + ((size_t)b * DQ_ + d) * LKV_ + kv) = v4;
            }
        }
    } else {
        _Float16* C16 = (_Float16*)C + (MODE >= 3 ? (size_t)z * sCb : 0);
        float*    C32 = (float*)C;
        float* rs = (MODE >= 3) ? rsum + (size_t)z * N : nullptr;
#pragma unroll
        for (int nt = 0; nt < 4; nt++) {
            const int ng = n0 + wc * 64 + nt * 16 + l;
            float inv = 0.f, srw = 0.f;
            if (MODE == 4) inv = 1.0f / rs[ng];
#pragma unroll
            for (int mt = 0; mt < 4; mt++) {
                const int mg = m0 + wr * 64 + mt * 16 + quad * 4;
                if (MODE == 0 || MODE == 1) {
                    const float4 bv = *(const float4*)(bias + mg);
                    if (MODE == 1) {
                        f32x4 v4 = { acc[mt][nt][0] + bv.x, acc[mt][nt][1] + bv.y,
                                     acc[mt][nt][2] + bv.z, acc[mt][nt][3] + bv.w };
                        *(f32x4*)(C32 + (size_t)ng * M + mg) = v4;
                    } else {
                        f16x4 v4 = { (_Float16)(acc[mt][nt][0] + bv.x),
                                     (_Float16)(acc[mt][nt][1] + bv.y),
                                     (_Float16)(acc[mt][nt][2] + bv.z),
                                     (_Float16)(acc[mt][nt][3] + bv.w) };
                        *(f16x4*)(C16 + (size_t)ng * M + mg) = v4;
                    }
                } else if (MODE == 3) {
                    f16x4 v4;
#pragma unroll
                    for (int r = 0; r < 4; r++) {
                        float e = __expf(acc[mt][nt][r] * scale);
                        v4[r] = (_Float16)e;
                        srw += e;
                    }
                    *(f16x4*)(C16 + (size_t)ng * M + mg) = v4;
                } else {   // MODE == 4
                    f16x4 v4;
#pragma unroll
                    for (int r = 0; r < 4; r++) v4[r] = (_Float16)(acc[mt][nt][r] * inv);
                    *(f16x4*)(C16 + (size_t)ng * M + mg) = v4;
                }
            }
            if (MODE == 3) {
                srw += __shfl_xor(srw, 16);
                srw += __shfl_xor(srw, 32);
                if (quad == 0) atomicAdd(&rs[ng], srw);
            }
        }
    }
}

// ---------------------------------------------------------------- launch
extern "C" void kernel_launch(void* const* d_in, const int* in_sizes, int n_in,
                              void* d_out, int out_size, void* d_ws, size_t ws_size,
                              hipStream_t stream) {
    const float* query = (const float*)d_in[0];
    const float* key   = (const float*)d_in[1];
    const float* value = (const float*)d_in[2];
    const float* Wk    = (const float*)d_in[3];
    const float* bk    = (const float*)d_in[4];
    const float* Wv    = (const float*)d_in[5];
    const float* bv    = (const float*)d_in[6];
    const float* Wo    = (const float*)d_in[7];
    const float* bo    = (const float*)d_in[8];
    float* out = (float*)d_out;

    const size_t NQ  = (size_t)B_ * LQ_ * DQ_;    // 8,388,608
    const size_t NKV = (size_t)B_ * LKV_ * DC_;   // 12,582,912

    _Float16* p    = (_Float16*)d_ws;
    _Float16* qbf  = p;  p += NQ;                  // later overwritten by ctx
    _Float16* kpbf = p;  p += NQ;                  // kpbf[b][kv][d]
    _Float16* vpT  = p;  p += NQ;                  // vpT[b][d][kv]
    _Float16* WkT  = p;  p += (size_t)DC_ * DQ_;
    _Float16* WvT  = p;  p += (size_t)DC_ * DQ_;
    _Float16* WoT  = p;  p += (size_t)DQ_ * DQ_;
    float*    rowsum = (float*)p;  p += 2 * (size_t)B_ * LQ_;   // 64 KB used
    _Float16* kbf  = p;  p += NKV;
    _Float16* vbf  = p;  p += NKV;
    _Float16* Pm   = kbf;    // P~[b][q][kv] aliases kbf.. (dead before S GEMM)
    _Float16* ctx  = qbf;    // ctx[b][q][d]; qbf dead after S GEMM

    const size_t base_bytes = (size_t)((char*)kbf - (char*)d_ws);
    const bool full = ws_size >= base_bytes + (size_t)B_ * LQ_ * LKV_ * 2 + 1024;

    hipMemsetAsync(rowsum, 0, (size_t)B_ * LQ_ * 4, stream);

    pack_qkv<<<dim3((unsigned)((NQ + 2 * NKV) / 8 / 256)), 256, 0, stream>>>(
        query, key, value, qbf, kbf, vbf);
    pack_w<<<dim3((2 * DC_ * DQ_ + DQ_ * DQ_) / 256), 256, 0, stream>>>(
        Wk, Wv, Wo, WkT, WvT, WoT);

    // K-proj: D[d][kv] -> kpbf[kv][d].  M=512(d), N=16384(kv), K=768
    gemm128<0><<<dim3(4, 128), 256, 0, stream>>>(WkT, kbf, bk, nullptr, kpbf,
                                                 512, 16384, DC_, 0, 0, 0);
    // V-proj: D[kv][d] -> vpT[b][d][kv]. M=16384(kv), N=512(d), K=768
    gemm128<2><<<dim3(128, 4), 256, 0, stream>>>(vbf, WvT, bv, nullptr, vpT,
                                                 16384, DQ_, DC_, 0, 0, 0);

    if (full) {
        // S: D[kv][q] -> P~[q][kv] = exp(scale*S). M=2048, N=2048, K=512
        gemm128<3><<<dim3(16, 16, B_), 256, 0, stream>>>(
            kpbf, qbf, nullptr, rowsum, Pm, LKV_, LQ_, DQ_,
            (long)LKV_ * DQ_, (long)LQ_ * DQ_, (long)LQ_ * LKV_);
        // PV: D[d][q] -> ctx[q][d] / rowsum[q]. M=512, N=2048, K=2048
        gemm128<4><<<dim3(4, 16, B_), 256, 0, stream>>>(
            vpT, Pm, nullptr, rowsum, ctx, DQ_, LQ_, LKV_,
            (long)DQ_ * LKV_, (long)LQ_ * LKV_, (long)LQ_ * DQ_);
    } else {
        for (int h = 0; h < 2; h++) {
            const int b0 = h * 4;
            gemm128<3><<<dim3(16, 16, 4), 256, 0, stream>>>(
                kpbf + (size_t)b0 * LKV_ * DQ_, qbf + (size_t)b0 * LQ_ * DQ_,
                nullptr, rowsum + (size_t)b0 * LQ_, Pm,
                LKV_, LQ_, DQ_,
                (long)LKV_ * DQ_, (long)LQ_ * DQ_, (long)LQ_ * LKV_);
            gemm128<4><<<dim3(4, 16, 4), 256, 0, stream>>>(
                vpT + (size_t)b0 * DQ_ * LKV_, Pm,
                nullptr, rowsum + (size_t)b0 * LQ_, ctx + (size_t)b0 * LQ_ * DQ_,
                DQ_, LQ_, LKV_,
                (long)DQ_ * LKV_, (long)LQ_ * LKV_, (long)LQ_ * DQ_);
        }
    }

    // out-proj: D[e][q] -> out[q][e] f32. M=512, N=16384, K=512
    gemm128<1><<<dim3(4, 128), 256, 0, stream>>>(WoT, ctx, bo, nullptr, out,
                                                 512, 16384, DQ_, 0, 0, 0);
}

// Round 5
// 327.496 us; speedup vs baseline: 1.1406x; 1.1406x over previous
//
#include <hip/hip_runtime.h>

// CrossAttention MI355X — round 4:
//  * LDS-bounce epilogues -> fully coalesced 16B/lane output stores (all modes)
//  * XCD swizzle: batch == XCD for attention GEMMs; B-tile sharers adjacent
//  * BK=64 staging with XOR chunk swizzle -> conflict-free ds_read_b128
//  * Q/K/V staged as raw f32 (cvt in-register) -> pack_qkv kernel deleted
//
//   out = softmax(Q (K Wk + bk)^T * scale) (V Wv + bv) Wo + bo
//   softmax(S) V = (exp(S) V) / rowsum(exp(S))   (scores tiny, no max-sub)
//
// GEMM modes (D[m][n] = A[m,:]·B[n,:]^T):
//   0: K-proj  A=WkT(512x768)  B=key f32(16384x768)  -> kpbf[kv][d]    +bk[m]
//   1: outproj A=WoT(512x512)  B=ctx f16(16384x512)  -> out[q][e] f32  +bo[m]
//   2: V-proj  A=WvT(512x768)  B=value f32           -> vpT[b][d][kv]  +bv[m]
//   3: S       A=kpbf(2048x512) B=query f32(2048x512)-> P~[q][kv]=exp(scale*S), rowsum atomics
//   4: PV      A=vpT(512x2048)  B=P~ f16(2048x2048)  -> ctx[q][d] * 1/rowsum[q]

typedef _Float16 f16x8 __attribute__((ext_vector_type(8)));
typedef _Float16 f16x4 __attribute__((ext_vector_type(4)));
typedef float    f32x4 __attribute__((ext_vector_type(4)));

#define B_    8
#define LQ_   2048
#define LKV_  2048
#define DQ_   512
#define DC_   768

#define AS1 __attribute__((address_space(1)))
#define AS3 __attribute__((address_space(3)))

__device__ __forceinline__ void gload16(const void* g, void* l) {
    // LDS dest is wave-uniform base; HW scatters lane i -> base + i*16
    __builtin_amdgcn_global_load_lds((const AS1 void*)g, (AS3 void*)l, 16, 0, 0);
}

// ------------------------------------------------- fused weight transpose+cvt
__global__ __launch_bounds__(256) void pack_w(const float* __restrict__ Wk,
                                              const float* __restrict__ Wv,
                                              const float* __restrict__ Wo,
                                              _Float16* __restrict__ WkT,
                                              _Float16* __restrict__ WvT,
                                              _Float16* __restrict__ WoT) {
    const int NKW = DC_ * DQ_;   // 393216
    int id = blockIdx.x * 256 + threadIdx.x;
    const float* W; _Float16* WT; int off, K;
    if (id < NKW)           { W = Wk; WT = WkT; off = id;           K = DC_; }
    else if (id < 2 * NKW)  { W = Wv; WT = WvT; off = id - NKW;     K = DC_; }
    else                    { W = Wo; WT = WoT; off = id - 2 * NKW; K = DQ_; }
    int k = off / DQ_, n = off - k * DQ_;
    WT[(size_t)n * K + k] = (_Float16)W[off];
}

// ---------------------------------------------------------------- GEMM 128x128
template <int MODE, int BF32, int GM, int GZ>
__global__ __launch_bounds__(256, 3) void gemm_bk64(
        const _Float16* __restrict__ A, const void* __restrict__ Bv,
        const float* __restrict__ bias, float* __restrict__ rsum,
        void* __restrict__ C, int M, int N, int K,
        long sAb, long sBb, long sCb) {
    constexpr int BK = 64;
    constexpr int ABYTES = 128 * BK * 2;                     // 16 KB f16
    constexpr int BBYTES = 128 * BK * (BF32 ? 4 : 2);        // 32 / 16 KB
    constexpr int CSTR   = 136;                              // halfs (16B-aligned rows)
    constexpr int CBYTES = (MODE == 1) ? 64 * 132 * 4 : 128 * CSTR * 2;
    constexpr int STAGE  = ABYTES + BBYTES;
    constexpr int SMEM   = STAGE > CBYTES ? STAGE : CBYTES;
    __shared__ __align__(16) char smem[SMEM];
    _Float16* As = (_Float16*)smem;

    // XCD swizzle: xcd = lin%8 (HW round-robin heuristic)
    const int lin = blockIdx.x;
    const int xcd = lin & 7, slot = lin >> 3;
    int mx, ny, z;
    if (GZ == 8) { z = xcd; mx = slot % GM; ny = slot / GM; }
    else         { z = 0;   mx = slot % GM; ny = (slot / GM) * 8 + xcd; }
    const int m0 = mx * 128, n0 = ny * 128;

    const _Float16* Ab = A + (size_t)z * sAb;
    const int tid = threadIdx.x, wave = tid >> 6, lane = tid & 63;
    const int l = lane & 15, quad = lane >> 4;
    const int wr = wave >> 1, wc = wave & 1;

    f32x4 acc[4][4] = {};

    const int arl = lane >> 3, apc = lane & 7;    // f16 staging: 8 rows x 8 chunks/instr
    const int brl = lane >> 4, bpc = lane & 15;   // f32 staging: 4 rows x 16 chunks/instr

    for (int k0 = 0; k0 < K; k0 += BK) {
        // ---- stage A (f16, 128x64): 16 instr, wave takes 4. XOR chunk swizzle.
#pragma unroll
        for (int ii = 0; ii < 4; ii++) {
            const int i = wave + ii * 4;
            const int row = i * 8 + arl;
            const int cc = apc ^ (row & 7);
            gload16(Ab + (size_t)(m0 + row) * K + k0 + cc * 8, smem + i * 1024);
        }
        if constexpr (BF32) {
            const float* Bb = (const float*)Bv + (size_t)z * sBb;
#pragma unroll
            for (int ii = 0; ii < 8; ii++) {
                const int i = wave + ii * 4;
                const int row = i * 4 + brl;
                const int cc = bpc ^ (row & 7);
                gload16(Bb + (size_t)(n0 + row) * K + k0 + cc * 4,
                        smem + ABYTES + i * 1024);
            }
        } else {
            const _Float16* Bb = (const _Float16*)Bv + (size_t)z * sBb;
#pragma unroll
            for (int ii = 0; ii < 4; ii++) {
                const int i = wave + ii * 4;
                const int row = i * 8 + arl;
                const int cc = apc ^ (row & 7);
                gload16(Bb + (size_t)(n0 + row) * K + k0 + cc * 8,
                        smem + ABYTES + i * 1024);
            }
        }
        __syncthreads();

#pragma unroll
        for (int ks = 0; ks < 2; ks++) {
            f16x8 af[4], bf[4];
#pragma unroll
            for (int mt = 0; mt < 4; mt++) {
                const int R = wr * 64 + mt * 16 + l;
                const int cc = ks * 4 + quad;
                af[mt] = *(const f16x8*)&As[R * 64 + (cc ^ (R & 7)) * 8];
            }
            if constexpr (BF32) {
                const float* Bs = (const float*)(smem + ABYTES);
#pragma unroll
                for (int nt = 0; nt < 4; nt++) {
                    const int R = wc * 64 + nt * 16 + l;
                    const int c0 = ks * 8 + quad * 2;
                    float4 x = *(const float4*)&Bs[R * 64 + (c0 ^ (R & 7)) * 4];
                    float4 y = *(const float4*)&Bs[R * 64 + ((c0 + 1) ^ (R & 7)) * 4];
                    bf[nt] = (f16x8){ (_Float16)x.x, (_Float16)x.y, (_Float16)x.z, (_Float16)x.w,
                                      (_Float16)y.x, (_Float16)y.y, (_Float16)y.z, (_Float16)y.w };
                }
            } else {
                const _Float16* Bs = (const _Float16*)(smem + ABYTES);
#pragma unroll
                for (int nt = 0; nt < 4; nt++) {
                    const int R = wc * 64 + nt * 16 + l;
                    const int cc = ks * 4 + quad;
                    bf[nt] = *(const f16x8*)&Bs[R * 64 + (cc ^ (R & 7)) * 8];
                }
            }
#pragma unroll
            for (int mt = 0; mt < 4; mt++)
#pragma unroll
                for (int nt = 0; nt < 4; nt++)
                    acc[mt][nt] = __builtin_amdgcn_mfma_f32_16x16x32_f16(af[mt], bf[nt], acc[mt][nt], 0, 0, 0);
        }
        __syncthreads();
    }

    // ---------------- epilogue: acc -> LDS bounce -> coalesced wide stores
    const float scale = 0.044194173824159216f;   // 1/sqrt(512)

    if constexpr (MODE == 1) {
        // f32 out, two 64-row chunks through 33 KB Cs32
        float* Cs32 = (float*)smem;
        float* outp = (float*)C;
#pragma unroll
        for (int ch = 0; ch < 2; ch++) {
            if (wc == ch) {
#pragma unroll
                for (int nt = 0; nt < 4; nt++) {
                    const int row = nt * 16 + l;
#pragma unroll
                    for (int mt = 0; mt < 4; mt++) {
                        const int col = wr * 64 + mt * 16 + quad * 4;
                        const float4 bv = *(const float4*)(bias + m0 + col);
                        f32x4 v = { acc[mt][nt][0] + bv.x, acc[mt][nt][1] + bv.y,
                                    acc[mt][nt][2] + bv.z, acc[mt][nt][3] + bv.w };
                        *(f32x4*)&Cs32[row * 132 + col] = v;
                    }
                }
            }
            __syncthreads();
#pragma unroll
            for (int i = 0; i < 8; i++) {
                const int p = tid + i * 256;
                const int row = p >> 5, col = (p & 31) * 4;
                f32x4 v = *(const f32x4*)&Cs32[row * 132 + col];
                *(f32x4*)(outp + (size_t)(n0 + ch * 64 + row) * M + m0 + col) = v;
            }
            __syncthreads();
        }
        return;
    } else {
        _Float16* Cs = (_Float16*)smem;
        if constexpr (MODE == 2) {
            // Cs[m][n] (output row = d = m)
#pragma unroll
            for (int mt = 0; mt < 4; mt++) {
                const int cb = wr * 64 + mt * 16 + quad * 4;
                const float4 bv = *(const float4*)(bias + m0 + cb);
#pragma unroll
                for (int nt = 0; nt < 4; nt++) {
                    const int cn = wc * 64 + nt * 16 + l;
#pragma unroll
                    for (int r = 0; r < 4; r++)
                        Cs[(cb + r) * CSTR + cn] =
                            (_Float16)(acc[mt][nt][r] + ((const float*)&bv)[r]);
                }
            }
        } else {
            // Cs[n][m] (output row = n)
            float* rs = (MODE >= 3) ? rsum + (size_t)z * N : nullptr;
#pragma unroll
            for (int nt = 0; nt < 4; nt++) {
                const int row = wc * 64 + nt * 16 + l;
                float srw = 0.f, inv = 0.f;
                if (MODE == 4) inv = 1.0f / rs[n0 + row];
#pragma unroll
                for (int mt = 0; mt < 4; mt++) {
                    const int col = wr * 64 + mt * 16 + quad * 4;
                    f16x4 v4;
                    if constexpr (MODE == 0) {
                        const float4 bv = *(const float4*)(bias + m0 + col);
#pragma unroll
                        for (int r = 0; r < 4; r++)
                            v4[r] = (_Float16)(acc[mt][nt][r] + ((const float*)&bv)[r]);
                    } else if constexpr (MODE == 3) {
#pragma unroll
                        for (int r = 0; r < 4; r++) {
                            float e = __expf(acc[mt][nt][r] * scale);
                            v4[r] = (_Float16)e;
                            srw += e;
                        }
                    } else {
#pragma unroll
                        for (int r = 0; r < 4; r++)
                            v4[r] = (_Float16)(acc[mt][nt][r] * inv);
                    }
                    *(f16x4*)&Cs[row * CSTR + col] = v4;
                }
                if constexpr (MODE == 3) {
                    srw += __shfl_xor(srw, 16);
                    srw += __shfl_xor(srw, 32);
                    if (quad == 0) atomicAdd(&rs[n0 + row], srw);
                }
            }
        }
        __syncthreads();

        _Float16* ob;
        int ostride;
        if constexpr (MODE == 2) {
            const int bb = n0 >> 11, kv0 = n0 & 2047;
            ob = (_Float16*)C + ((size_t)bb * DQ_ + m0) * LKV_ + kv0;
            ostride = LKV_;
        } else {
            ob = (_Float16*)C + (MODE >= 3 ? (size_t)z * sCb : 0) + (size_t)n0 * M + m0;
            ostride = M;
        }
#pragma unroll
        for (int i = 0; i < 8; i++) {
            const int p = tid + i * 256;
            const int row = p >> 4, col = (p & 15) * 8;
            f16x8 v = *(const f16x8*)&Cs[row * CSTR + col];
            *(f16x8*)(ob + (size_t)row * ostride + col) = v;
        }
    }
}

// ---------------------------------------------------------------- launch
extern "C" void kernel_launch(void* const* d_in, const int* in_sizes, int n_in,
                              void* d_out, int out_size, void* d_ws, size_t ws_size,
                              hipStream_t stream) {
    const float* query = (const float*)d_in[0];
    const float* key   = (const float*)d_in[1];
    const float* value = (const float*)d_in[2];
    const float* Wk    = (const float*)d_in[3];
    const float* bk    = (const float*)d_in[4];
    const float* Wv    = (const float*)d_in[5];
    const float* bv    = (const float*)d_in[6];
    const float* Wo    = (const float*)d_in[7];
    const float* bo    = (const float*)d_in[8];
    float* out = (float*)d_out;

    const size_t NQ = (size_t)B_ * LQ_ * DQ_;    // 8,388,608

    _Float16* p    = (_Float16*)d_ws;
    _Float16* kpbf = p;  p += NQ;                  // kpbf[b][kv][d]; later reused as ctx
    _Float16* vpT  = p;  p += NQ;                  // vpT[b][d][kv]
    _Float16* WkT  = p;  p += (size_t)DC_ * DQ_;
    _Float16* WvT  = p;  p += (size_t)DC_ * DQ_;
    _Float16* WoT  = p;  p += (size_t)DQ_ * DQ_;
    float*    rowsum = (float*)p;  p += 2 * (size_t)B_ * LQ_;   // 64 KB
    _Float16* Pm   = p;  p += (size_t)B_ * LQ_ * LKV_;          // 67.1 MB
    _Float16* ctx  = kpbf;   // kpbf dead after S GEMM

    hipMemsetAsync(rowsum, 0, (size_t)B_ * LQ_ * 4, stream);
    pack_w<<<dim3((2 * DC_ * DQ_ + DQ_ * DQ_) / 256), 256, 0, stream>>>(
        Wk, Wv, Wo, WkT, WvT, WoT);

    // K-proj: D[d][kv] -> kpbf[kv][d]. M=512, N=16384, K=768, B=key f32
    gemm_bk64<0, 1, 4, 1><<<dim3(512), 256, 0, stream>>>(
        WkT, key, bk, nullptr, kpbf, 512, 16384, DC_, 0, 0, 0);
    // V-proj: D[d][kv] -> vpT[b][d][kv]. B=value f32
    gemm_bk64<2, 1, 4, 1><<<dim3(512), 256, 0, stream>>>(
        WvT, value, bv, nullptr, vpT, 512, 16384, DC_, 0, 0, 0);
    // S: D[kv][q] -> P~[q][kv] = exp(scale*S). M=2048, N=2048, K=512, B=query f32
    gemm_bk64<3, 1, 16, 8><<<dim3(2048), 256, 0, stream>>>(
        kpbf, query, nullptr, rowsum, Pm, LKV_, LQ_, DQ_,
        (long)LKV_ * DQ_, (long)LQ_ * DQ_, (long)LQ_ * LKV_);
    // PV: D[d][q] -> ctx[q][d] / rowsum[q]. M=512, N=2048, K=2048, B=P~ f16
    gemm_bk64<4, 0, 4, 8><<<dim3(512), 256, 0, stream>>>(
        vpT, Pm, nullptr, rowsum, ctx, DQ_, LQ_, LKV_,
        (long)DQ_ * LKV_, (long)LQ_ * LKV_, (long)LQ_ * DQ_);
    // out-proj: D[e][q] -> out[q][e] f32. M=512, N=16384, K=512, B=ctx f16
    gemm_bk64<1, 0, 4, 1><<<dim3(512), 256, 0, stream>>>(
        WoT, ctx, bo, nullptr, out, 512, 16384, DQ_, 0, 0, 0);
}